// Round 8
// baseline (110.594 us; speedup 1.0000x reference)
//
#include <hip/hip_runtime.h>

#define CIN  32
#define OCH  64
#define HH   56
#define WW   56
#define BB   4
#define OT   4                  // output channels per block
#define TH   8                  // output rows per block strip
#define NT   448                // threads = 8*56, 7 waves, zero waste
#define CG   8                  // channels per LDS phase
#define CPB  16                 // channels per block (2-way channel split)
#define HALO_H (TH + 2)         // 10
#define HALO_W (WW + 2)         // 58
#define CH_STRIDE (HALO_H * HALO_W)   // 580
#define STAGE (CG * CH_STRIDE)        // 4640
#define NJ   11                       // ceil(4640/448)
#define IMG  (HH * WW)          // 3136
#define NW   18432              // 64*32*3*3
#define OUTN (BB * OCH * IMG)   // 802816
#define WPK   16                // packed weights at float offset 16 (64B aligned)
#define WPART (WPK + NW)        // partials (16+18432)*4 B, 16B aligned

// plain v_min_f32, both operands VGPR: bypasses llvm.minnum canonicalization.
__device__ __forceinline__ float vmin(float a, float b) {
    float r;
    asm("v_min_f32 %0, %1, %2" : "=v"(r) : "v"(a), "v"(b));
    return r;
}

__global__ __launch_bounds__(256) void absmean_reduce(const float* __restrict__ w,
                                                      float* __restrict__ ws) {
    int idx = (blockIdx.x * 256 + threadIdx.x) * 4;   // 18 blocks * 256 * 4
    float4 v = *reinterpret_cast<const float4*>(w + idx);
    float s = fabsf(v.x) + fabsf(v.y) + fabsf(v.z) + fabsf(v.w);
    #pragma unroll
    for (int off = 32; off > 0; off >>= 1)
        s += __shfl_down(s, off);
    __shared__ float smem[4];
    int lane = threadIdx.x & 63, wv = threadIdx.x >> 6;
    if (lane == 0) smem[wv] = s;
    __syncthreads();
    if (threadIdx.x == 0)
        atomicAdd(ws, smem[0] + smem[1] + smem[2] + smem[3]);
}

// repack w[o][c][t] -> wp[ot][c][oo*9+t]  (ot=o/4, oo=o%4); 36 floats per
// (ot,c) cell, 144 B, 16B-aligned -> 9x dwordx4 per channel in the hot loop.
__global__ __launch_bounds__(256) void repack_w(const float* __restrict__ w,
                                                float* __restrict__ wp) {
    int i = blockIdx.x * 256 + threadIdx.x;     // 72 blocks, exact 18432
    int t  = i % 9;
    int oc = i / 9;
    int c  = oc % CIN;
    int o  = oc / CIN;
    wp[((o >> 2) * CIN + c) * 36 + (o & 3) * 9 + t] = w[i];
}

// Block = 448 threads = 8x56 strip x 4 out-ch x 16 in-ch. x zero-padded in
// LDS (lgkm, in-order); weights as vector dwordx4 loads of uniform addresses
// (vmcnt domain) -> NO SMEM in the loop, so no lgkmcnt(0) drains.
__global__ __launch_bounds__(NT) void minconv_kernel(const float* __restrict__ x,
                                                     const float* __restrict__ wpk,
                                                     float* __restrict__ part) {
    __shared__ float xs[STAGE];         // 18560 B

    const int tid = threadIdx.x;
    const int ht  = blockIdx.x;         // 0..6
    const int ot  = blockIdx.y;         // 0..15
    const int o0  = ot * OT;
    const int b   = blockIdx.z >> 1;    // 0..3
    const int cs  = blockIdx.z & 1;     // channel split 0/1
    const int c0  = cs * CPB;
    const int h0  = ht * TH;

    const int ph = tid / WW;            // 0..7
    const int pw = tid - ph * WW;       // 0..55

    const float* xb = x + (b * CIN + c0) * IMG;

    // packed-weight base, laundered into a VGPR so LLVM cannot re-scalarize
    // these loads into s_load (keeps them in the vmcnt domain).
    const float* wp_ = wpk + ot * (CIN * 36);
    {
        unsigned long long a = (unsigned long long)wp_;
        asm("" : "+v"(a));
        wp_ = (const float*)a;
    }

    // staging address precompute (reused across both phases)
    int  srel[NJ];
    bool sok[NJ];
    #pragma unroll
    for (int j = 0; j < NJ; ++j) {
        int i  = tid + j * NT;
        int c  = i / CH_STRIDE;
        int r  = (i - c * CH_STRIDE) / HALO_W;
        int cc = i - c * CH_STRIDE - r * HALO_W;
        int gh = h0 - 1 + r;
        int gw = cc - 1;
        sok[j]  = (i < STAGE) & ((unsigned)gh < (unsigned)HH) & ((unsigned)gw < (unsigned)WW);
        srel[j] = c * IMG + gh * WW + gw;
    }

    float acc[OT] = {0.f, 0.f, 0.f, 0.f};

    for (int cg = 0; cg < CPB; cg += CG) {
        __syncthreads();                // protect previous phase's reads
        const float* xc = xb + cg * IMG;
        #pragma unroll
        for (int j = 0; j < NJ; ++j) {
            float v = 0.f;
            if (sok[j]) v = xc[srel[j]];
            int i = tid + j * NT;
            if (j < NJ - 1) xs[i] = v;
            else if (i < STAGE) xs[i] = v;
        }
        __syncthreads();

        const float* xp0 = xs + ph * HALO_W + pw;
        #pragma unroll 2
        for (int c = 0; c < CG; ++c) {
            // weights for this channel: 36 floats = 9 x global_load_dwordx4
            const float4* wq = (const float4*)(wp_ + (c0 + cg + c) * 36);
            float wreg[36];
            #pragma unroll
            for (int j = 0; j < 9; ++j) {
                float4 q = wq[j];
                wreg[4 * j + 0] = q.x;
                wreg[4 * j + 1] = q.y;
                wreg[4 * j + 2] = q.z;
                wreg[4 * j + 3] = q.w;
            }
            const float* xp = xp0 + c * CH_STRIDE;
            float xv[9];
            #pragma unroll
            for (int kh = 0; kh < 3; ++kh)
                #pragma unroll
                for (int kw = 0; kw < 3; ++kw)
                    xv[kh * 3 + kw] = xp[kh * HALO_W + kw];
            #pragma unroll
            for (int oo = 0; oo < OT; ++oo)
                #pragma unroll
                for (int t = 0; t < 9; ++t)
                    acc[oo] += vmin(xv[t], wreg[oo * 9 + t]);
        }
    }

    float* pb = part + cs * OUTN + (b * OCH + o0) * IMG + (h0 + ph) * WW + pw;
    #pragma unroll
    for (int oo = 0; oo < OT; ++oo)
        pb[oo * IMG] = acc[oo];
}

// out[i] = mu * (part0[i] + part1[i]); float4 over 802816 elems.
__global__ __launch_bounds__(256) void combine_kernel(const float* __restrict__ ws,
                                                      float* __restrict__ out) {
    const float mu = ws[0] * (1.0f / (float)NW);
    const float* p = ws + WPART;
    int i = (blockIdx.x * 256 + threadIdx.x) * 4;   // 784 blocks, exact
    float4 a = *reinterpret_cast<const float4*>(p + i);
    float4 c = *reinterpret_cast<const float4*>(p + OUTN + i);
    float4 r;
    r.x = mu * (a.x + c.x);
    r.y = mu * (a.y + c.y);
    r.z = mu * (a.z + c.z);
    r.w = mu * (a.w + c.w);
    *reinterpret_cast<float4*>(out + i) = r;
}

extern "C" void kernel_launch(void* const* d_in, const int* in_sizes, int n_in,
                              void* d_out, int out_size, void* d_ws, size_t ws_size,
                              hipStream_t stream) {
    const float* x   = (const float*)d_in[0];   // 4*32*56*56
    const float* w   = (const float*)d_in[1];   // 64*32*3*3
    float*       out = (float*)d_out;           // 4*64*56*56
    float*       ws  = (float*)d_ws;

    hipMemsetAsync(ws, 0, sizeof(float), stream);
    absmean_reduce<<<NW / (256 * 4), 256, 0, stream>>>(w, ws);
    repack_w<<<NW / 256, 256, 0, stream>>>(w, ws + WPK);
    dim3 grid(HH / TH, OCH / OT, BB * 2);       // 7 x 16 x 8 = 896 blocks
    minconv_kernel<<<grid, NT, 0, stream>>>(x, ws + WPK, ws + WPART);
    combine_kernel<<<OUTN / (256 * 4), 256, 0, stream>>>(ws, out);
}